// Round 11
// baseline (269.640 us; speedup 1.0000x reference)
//
#include <hip/hip_runtime.h>
#include <stdint.h>

#define B_SZ 8192
#define N_F 12
#define H_DIM 512
#define K_DIM 1024
#define V_DIM 256

typedef __attribute__((ext_vector_type(8))) __bf16 bf16x8;
typedef __attribute__((ext_vector_type(4))) float f32x4;

// tanh-approx GELU, sigmoid form, DIVISION-FREE (v_rcp instead of IEEE div;
// ~1 ulp rcp error is noise vs the 1e-3 approx error; absmax margin ~3x).
__device__ inline float gelu_f(float x) {
  const float u = x * x;
  const float nt = x * fmaf(-0.071354814f, u, -1.5957691216f);
  return x * __builtin_amdgcn_rcpf(1.0f + __expf(nt));
}

__device__ inline void gld_lds16(const void* g, void* l) {
  __builtin_amdgcn_global_load_lds(
      (const __attribute__((address_space(1))) void*)g,
      (__attribute__((address_space(3))) void*)l, 16, 0, 0);
}

// ---------------------------------------------------------------------------
// Kernel 1: wave-per-row. Lane l owns dims [l*8, l*8+8) of H=512.
// Emits BOTH activation halves per n, pre-swizzled (chunk c at slot c^(b&7)
// within each 64-elem K-group):
//   masked-sums half -> actA  = d_out alias, [B][N][512] bf16
//   ctx half         -> ctx2  = ws,          [B][N][512] bf16
// k_gemm is then a PURE GEMM. At its HBM floor (~271 MB traffic).
// ---------------------------------------------------------------------------
__global__ __launch_bounds__(256, 4) void k_prep(
    const float* __restrict__ ie, const int* __restrict__ feat,
    const float* __restrict__ tab, const float* __restrict__ gam,
    const float* __restrict__ bet, __bf16* actA, __bf16* __restrict__ ctx2) {
  const int lane = threadIdx.x & 63;
  const int b = blockIdx.x * 4 + (threadIdx.x >> 6);

  const float* cb = ie + (size_t)b * H_DIM + lane * 8;
  float4 c0 = *(const float4*)cb;
  float4 c1 = *(const float4*)(cb + 4);
  float s = c0.x + c0.y + c0.z + c0.w + c1.x + c1.y + c1.z + c1.w;
  float q = c0.x * c0.x + c0.y * c0.y + c0.z * c0.z + c0.w * c0.w +
            c1.x * c1.x + c1.y * c1.y + c1.z * c1.z + c1.w * c1.w;
#pragma unroll
  for (int o = 1; o < 64; o <<= 1) {
    s += __shfl_xor(s, o, 64);
    q += __shfl_xor(q, o, 64);
  }
  const float S1 = s, Q1 = q;

  const float4 gl0 = *(const float4*)(gam + lane * 8);
  const float4 gl1 = *(const float4*)(gam + lane * 8 + 4);
  const float4 el0 = *(const float4*)(bet + lane * 8);
  const float4 el1 = *(const float4*)(bet + lane * 8 + 4);
  const float4 g0 = *(const float4*)(gam + H_DIM + lane * 8);
  const float4 g1 = *(const float4*)(gam + H_DIM + lane * 8 + 4);
  const float4 e0 = *(const float4*)(bet + H_DIM + lane * 8);
  const float4 e1 = *(const float4*)(bet + H_DIM + lane * 8 + 4);

  float r[8];
#pragma unroll
  for (int i = 0; i < 8; ++i) r[i] = 0.f;

  const int sw = (lane & ~7) | ((lane & 7) ^ (b & 7));
  __bf16* arowM = actA + (size_t)b * N_F * H_DIM + sw * 8;
  __bf16* arowC = ctx2 + (size_t)b * N_F * H_DIM + sw * 8;

  for (int n = 0; n < N_F; ++n) {
    s = 0.f; q = 0.f;
#pragma unroll
    for (int i = 0; i < 8; ++i) { s += r[i]; q += r[i] * r[i]; }
#pragma unroll
    for (int o = 1; o < 64; o <<= 1) {
      s += __shfl_xor(s, o, 64);
      q += __shfl_xor(q, o, 64);
    }
    const float mean = (S1 + s) * (1.0f / 1024.0f);
    const float var = (Q1 + q) * (1.0f / 1024.0f) - mean * mean;
    const float rs = __builtin_amdgcn_rsqf(var + 1e-5f);

    // issue next gather early so latency hides under the gelu work
    float4 t0, t1;
    const bool have = (n < N_F - 1);
    if (have) {
      const int f = feat[b * N_F + n];
      const float* tr = tab + ((size_t)n * V_DIM + f) * H_DIM + lane * 8;
      t0 = *(const float4*)tr;
      t1 = *(const float4*)(tr + 4);
    }

    // ctx half (k in [0,512)) -> ctx2
    bf16x8 pc;
    pc[0] = (__bf16)gelu_f((c0.x - mean) * rs * gl0.x + el0.x);
    pc[1] = (__bf16)gelu_f((c0.y - mean) * rs * gl0.y + el0.y);
    pc[2] = (__bf16)gelu_f((c0.z - mean) * rs * gl0.z + el0.z);
    pc[3] = (__bf16)gelu_f((c0.w - mean) * rs * gl0.w + el0.w);
    pc[4] = (__bf16)gelu_f((c1.x - mean) * rs * gl1.x + el1.x);
    pc[5] = (__bf16)gelu_f((c1.y - mean) * rs * gl1.y + el1.y);
    pc[6] = (__bf16)gelu_f((c1.z - mean) * rs * gl1.z + el1.z);
    pc[7] = (__bf16)gelu_f((c1.w - mean) * rs * gl1.w + el1.w);
    *(bf16x8*)(arowC + (size_t)n * H_DIM) = pc;

    // masked-sums half (k in [512,1024)) -> actA (= d_out alias)
    bf16x8 pk;
    pk[0] = (__bf16)gelu_f((r[0] - mean) * rs * g0.x + e0.x);
    pk[1] = (__bf16)gelu_f((r[1] - mean) * rs * g0.y + e0.y);
    pk[2] = (__bf16)gelu_f((r[2] - mean) * rs * g0.z + e0.z);
    pk[3] = (__bf16)gelu_f((r[3] - mean) * rs * g0.w + e0.w);
    pk[4] = (__bf16)gelu_f((r[4] - mean) * rs * g1.x + e1.x);
    pk[5] = (__bf16)gelu_f((r[5] - mean) * rs * g1.y + e1.y);
    pk[6] = (__bf16)gelu_f((r[6] - mean) * rs * g1.z + e1.z);
    pk[7] = (__bf16)gelu_f((r[7] - mean) * rs * g1.w + e1.w);
    *(bf16x8*)(arowM + (size_t)n * H_DIM) = pk;

    if (have) {
      r[0] += t0.x; r[1] += t0.y; r[2] += t0.z; r[3] += t0.w;
      r[4] += t1.x; r[5] += t1.y; r[6] += t1.z; r[7] += t1.w;
    }
  }
}

// ---------------------------------------------------------------------------
// Kernel 2: pred_W [N][K][V] fp32 -> Wt [N][V][K] bf16, chunk-swizzled by v&7.
// ---------------------------------------------------------------------------
__global__ __launch_bounds__(256) void k_wt(const float* __restrict__ W,
                                            __bf16* __restrict__ Wt) {
  __shared__ float tile[32][33];
  const int bid = blockIdx.x;
  const int n = bid >> 8;
  const int rem = bid & 255;
  const int kt = rem >> 3, vt = rem & 7;
  const int tx = threadIdx.x & 31, ty = threadIdx.x >> 5;
  const float* src = W + (size_t)n * K_DIM * V_DIM;
#pragma unroll
  for (int i = 0; i < 4; ++i) {
    const int k = kt * 32 + ty + i * 8;
    tile[ty + i * 8][tx] = src[(size_t)k * V_DIM + vt * 32 + tx];
  }
  __syncthreads();
  __bf16* dst = Wt + (size_t)n * V_DIM * K_DIM;
  const int t = threadIdx.x;
  if (t < 128) {
    const int v_l = t >> 2, c_l = t & 3;
    const int v = vt * 32 + v_l;
    bf16x8 pk;
#pragma unroll
    for (int e = 0; e < 8; ++e) pk[e] = (__bf16)tile[c_l * 8 + e][v_l];
    const int gc = kt * 4 + c_l;
    const int swc = (gc & ~7) | ((gc & 7) ^ (v & 7));
    *(bf16x8*)(dst + (size_t)v * K_DIM + swc * 8) = pk;
  }
}

// ---------------------------------------------------------------------------
// Kernel 3: PURE GEMM, R10 geometry + single-barrier double-buffer (T3-min,
// m230 recipe). grid = (B/64, N), 256 threads (4 waves, 1x4). BM=64 BN=256
// BK=64. LDS 2x40 = 80 KB -> 2 blocks/CU. Per K-step: stage(kt+1)->buf^1
// FIRST (10 glds/wave in flight), compute(buf) (ds_reads + 32 MFMA hides
// the load latency), then ONE __syncthreads (vmcnt0+lgkm0+barrier: tile
// kt+1 landed, and compute-of-buf done before next step overwrites it).
// K order: kt<8 -> ctx2, kt>=8 -> actA.
// Alias: actA aliases d_out; block (b-block, n) exclusively owns its
// act/out cells (BN=256 = full V); reads precede epilogue writes in-block.
// ---------------------------------------------------------------------------
__global__ __launch_bounds__(256, 2) void k_gemm(
    const __bf16* __restrict__ ctx2, const __bf16* actA,
    const __bf16* __restrict__ Wt, const float* __restrict__ bias,
    float* out) {
  constexpr int BM = 64, BN = 256, BK = 64;
  __shared__ __align__(16) __bf16 As[2][BM * BK];  // 2 x 8 KB
  __shared__ __align__(16) __bf16 Ws[2][BN * BK];  // 2 x 32 KB (80 KB total)

  const int n = blockIdx.y;
  const int b0 = blockIdx.x * BM;
  const int t = threadIdx.x;
  const int lane = t & 63;
  const int w = t >> 6;  // 0..3, owns v block w*64
  const int l15 = lane & 15;
  const int lq = lane >> 4;
  const int lr8 = lane >> 3;
  const int lo8 = lane & 7;

  const __bf16* Wtn = Wt + (size_t)n * V_DIM * K_DIM;

  f32x4 acc[4][4];
#pragma unroll
  for (int i = 0; i < 4; ++i)
#pragma unroll
    for (int j = 0; j < 4; ++j) acc[i][j] = (f32x4){0.f, 0.f, 0.f, 0.f};

  // stage tile kt into buffer buf: 8 W-glds + 2 A-glds per wave
  auto stage = [&](int buf, int kt) {
#pragma unroll
    for (int p = 0; p < 8; ++p) {
      const int r0 = w * 64 + p * 8;
      gld_lds16(Wtn + (size_t)(r0 + lr8) * K_DIM + kt * BK + lo8 * 8,
                &Ws[buf][r0 * BK]);
    }
    const __bf16* src = (kt < 8) ? ctx2 : actA;
    const int kc = (kt < 8) ? kt * 64 : (kt - 8) * 64;
#pragma unroll
    for (int p = 0; p < 2; ++p) {
      const int r0 = w * 16 + p * 8;
      gld_lds16(src + ((size_t)(b0 + r0 + lr8) * N_F + n) * H_DIM + kc + lo8 * 8,
                &As[buf][r0 * BK]);
    }
  };

  stage(0, 0);
  __syncthreads();

#pragma unroll
  for (int kt = 0; kt < 16; ++kt) {
    const int cur = kt & 1;
    // --- issue next tile's staging BEFORE compute (overlaps with MFMA) ---
    if (kt < 15) stage(cur ^ 1, kt + 1);
    // --- compute current buffer: 2 MFMA k-steps, swizzled fragment reads ---
#pragma unroll
    for (int ks = 0; ks < 2; ++ks) {
      const int cs = ks * 4 + lq;
      bf16x8 af[4], bb[4];
#pragma unroll
      for (int i = 0; i < 4; ++i) {
        const int row = i * 16 + l15;  // A rows 0..63
        af[i] = *(const bf16x8*)(&As[cur][row * BK + ((cs ^ (row & 7)) << 3)]);
      }
#pragma unroll
      for (int j = 0; j < 4; ++j) {
        const int row = w * 64 + j * 16 + l15;  // V rows, wave-owned block
        bb[j] = *(const bf16x8*)(&Ws[cur][row * BK + ((cs ^ (row & 7)) << 3)]);
      }
#pragma unroll
      for (int i = 0; i < 4; ++i)
#pragma unroll
        for (int j = 0; j < 4; ++j)
          acc[i][j] = __builtin_amdgcn_mfma_f32_16x16x32_bf16(af[i], bb[j],
                                                              acc[i][j], 0, 0, 0);
    }
    // one barrier per step: next tile landed; this buffer safe to overwrite
    __syncthreads();
  }

  // epilogue: C/D layout col=lane&15, row=(lane>>4)*4+reg
#pragma unroll
  for (int j = 0; j < 4; ++j) {
    const int v = w * 64 + j * 16 + l15;
    const float bv = bias[n * V_DIM + v];
#pragma unroll
    for (int i = 0; i < 4; ++i) {
      const int rb = i * 16 + lq * 4;
#pragma unroll
      for (int r = 0; r < 4; ++r) {
        out[((size_t)(b0 + rb + r) * N_F + n) * V_DIM + v] = acc[i][j][r] + bv;
      }
    }
  }
}

// ---------------------------------------------------------------------------
extern "C" void kernel_launch(void* const* d_in, const int* in_sizes, int n_in,
                              void* d_out, int out_size, void* d_ws, size_t ws_size,
                              hipStream_t stream) {
  const float* ie = (const float*)d_in[0];
  const int* feat = (const int*)d_in[1];
  const float* tab = (const float*)d_in[2];
  const float* gam = (const float*)d_in[3];
  const float* bet = (const float*)d_in[4];
  const float* predW = (const float*)d_in[5];
  const float* predb = (const float*)d_in[6];
  float* out = (float*)d_out;

  // masked-half activation aliases d_out (exactly out_size bytes)
  __bf16* actA = (__bf16*)d_out;

  char* ws = (char*)d_ws;
  __bf16* ctx2 = (__bf16*)ws;                        // 100,663,296 B
  __bf16* Wt = (__bf16*)(ws + 100663296);            //   6,291,456 B

  hipLaunchKernelGGL(k_prep, dim3(B_SZ / 4), dim3(256), 0, stream, ie, feat,
                     tab, gam, bet, actA, ctx2);
  hipLaunchKernelGGL(k_wt, dim3(3072), dim3(256), 0, stream, predW, Wt);
  hipLaunchKernelGGL(k_gemm, dim3(B_SZ / 64, N_F), dim3(256), 0, stream,
                     ctx2, actA, Wt, predb, out);
}